// Round 9
// baseline (777.161 us; speedup 1.0000x reference)
//
#include <hip/hip_runtime.h>
#include <stdint.h>

typedef unsigned long long ull;
typedef int i32x4 __attribute__((ext_vector_type(4)));
typedef int i32x16 __attribute__((ext_vector_type(16)));
#define BB 256

// ---------------- workspace layout (bytes) ----------------
static const size_t OFF_CONV  = 0;              // 67108864 (conv frag / NHWC int16)
static const size_t OFF_ACT1  = 67108864;       // 37879808 (L1 in; later L3 in first 21233664)
static const size_t OFF_ACT2  = 104988672;      // 21233664 (L2 in)
static const size_t OFF_BITS4 = 126222336;      // 819200   (L4 in bitplanes)
static const size_t OFF_BITS5 = 127041536;      // 409600   (L5 in bitplanes)
static const size_t OFF_WBPC  = 127451136;      // 55296    (popcount weights L4,L5)
static const size_t OFF_WPK   = 127506432;      // 1474560  (mfma weights L1,L2,L3)
static const size_t OFF_S     = 128980992;      // 6144
static const size_t OFF_SS    = 128987136;      // 12288
static const size_t OFF_ATHR  = 128999424;      // 6144
static const size_t OFF_BTHR  = 129005568;      // 6144
static const size_t OFF_H     = 129011712;      // 2097152
static const size_t OFF_XB    = 131108864;      // 98304 xbits + 512 w27
static const size_t WS_NEEDED = 131207680;

#define SWZA(o) ((o) ^ (((((o) >> 7) ^ ((o) >> 10)) & 7) << 4))

// ---------------- small kernels ----------------

__global__ void zero_stats_k(int* __restrict__ S, ull* __restrict__ SS) {
  int i = blockIdx.x * blockDim.x + threadIdx.x;
  if (i < 6 * 256) { S[i] = 0; SS[i] = 0ull; }
}

// popcount-conv weights (L4/L5)
__global__ void pack_w_k(const float* __restrict__ w, uint32_t* __restrict__ out,
                         int co, int ci) {
  int K32 = ci >> 5;
  int total = 9 * K32 * co;
  int idx = blockIdx.x * blockDim.x + threadIdx.x;
  if (idx >= total) return;
  int c  = idx % co;
  int tk = idx / co;
  int k  = tk % K32;
  int t  = tk / K32;
  uint32_t word = 0;
  const float* wc = w + (size_t)c * ci * 9 + t;
  for (int j = 0; j < 32; ++j)
    if (wc[(size_t)(k * 32 + j) * 9] >= 0.f) word |= (1u << j);
  out[idx] = word;
}

// MFMA fragment-packed int8 weights
__global__ void pack_wmfma_k(const float* __restrict__ w, signed char* __restrict__ out,
                             int co, int ci) {
  int KT = ci >> 5;
  int total = (co >> 5) * 9 * KT * 64;
  int idx = blockIdx.x * blockDim.x + threadIdx.x;
  if (idx >= total) return;
  int l   = idx & 63;
  int ctk = idx >> 6;
  int kt  = ctk % KT; int tmp = ctk / KT;
  int t   = tmp % 9;  int ct  = tmp / 9;
  int co_ = ct * 32 + (l & 31);
  int ci0 = kt * 32 + (l >> 5) * 16;
  const float* wp = w + ((size_t)co_ * ci + ci0) * 9 + t;
  int dw[4];
#pragma unroll
  for (int jj = 0; jj < 4; ++jj) {
    uint32_t d = 0;
#pragma unroll
    for (int bb = 0; bb < 4; ++bb) {
      float f = wp[(size_t)(jj * 4 + bb) * 9];
      d |= ((f >= 0.f) ? 0x01u : 0xFFu) << (8 * bb);
    }
    dw[jj] = (int)d;
  }
  *(i32x4*)(out + (size_t)idx * 16) = *(i32x4*)&dw[0];
}

__global__ void pack_x_k(const float* __restrict__ x, uint32_t* __restrict__ xbits) {
  int idx = blockIdx.x * 256 + threadIdx.x;
  if (idx >= 24576) return;
  const float* xp = x + (size_t)idx * 32;
  uint32_t w = 0;
#pragma unroll
  for (int j = 0; j < 32; ++j) if (xp[j] >= 0.f) w |= (1u << j);
  xbits[idx] = w;
}

__global__ void pack_w0_k(const float* __restrict__ w0, uint32_t* __restrict__ w27) {
  int co = threadIdx.x;
  uint32_t w = 0;
#pragma unroll
  for (int t = 0; t < 27; ++t) if (w0[co * 27 + t] >= 0.f) w |= (1u << t);
  w27[co] = w;
}

// layer 0: 27-bit popcount conv
__global__ void __launch_bounds__(256) conv0x_k(
    const uint32_t* __restrict__ xbits, const uint32_t* __restrict__ w27,
    short* __restrict__ convout, int* __restrict__ Sg, ull* __restrict__ SSg) {
  int b  = blockIdx.x >> 2;
  int rg = blockIdx.x & 3;
  __shared__ uint32_t a27s[256];
  __shared__ uint32_t wlds[128];
  __shared__ int sS[256], sSS[256];
  int tid = threadIdx.x;
  if (tid < 128) wlds[tid] = w27[tid];

  int p = rg * 256 + tid;
  int y = p >> 5, xx = p & 31;
  const uint32_t* xb = xbits + (size_t)b * 96;
  uint32_t a27 = 0;
#pragma unroll
  for (int c = 0; c < 3; ++c)
#pragma unroll
    for (int kh = 0; kh < 3; ++kh) {
      int iy = y + kh - 1;
      uint32_t r = (iy >= 0 && iy < 32) ? xb[c * 32 + iy] : 0u;
      uint32_t bits3 = (uint32_t)((((uint64_t)r) << 1) >> xx) & 7u;
      a27 |= bits3 << (c * 9 + kh * 3);
    }
  a27s[tid] = a27;
  __syncthreads();

  int co = tid & 127, half = tid >> 7;
  uint32_t wv = wlds[co];
  int S = 0, SS = 0;
  int base = rg * 256 + half * 128;
  short* cb = convout + ((size_t)b * 1024 + base) * 128 + co;
  for (int i = 0; i < 128; ++i) {
    uint32_t a = a27s[half * 128 + i];
    int v = 27 - 2 * __popc(a ^ wv);
    S += v; SS += v * v;
    cb[(size_t)i * 128] = (short)v;
  }
  sS[tid] = S; sSS[tid] = SS;
  __syncthreads();
  if (tid < 128) {
    atomicAdd(&Sg[tid], sS[tid] + sS[tid + 128]);
    atomicAdd(&SSg[tid], (ull)(long long)(sSS[tid] + sSS[tid + 128]));
  }
}

// integer threshold from batch stats
__global__ void finalize_k(const int* __restrict__ S, const ull* __restrict__ SS,
                           int* __restrict__ A, int* __restrict__ B,
                           const float* __restrict__ gamma, const float* __restrict__ beta,
                           int co, int N) {
  int c = threadIdx.x;
  if (c >= co) return;
  double m  = (double)S[c] / (double)N;
  double e2 = (double)SS[c] / (double)N;
  double inv = 1.0 / sqrt(e2 - m * m + 1e-5);
  float gg = gamma[c], bb = beta[c];
  int Ai, Bi;
  if (gg > 0.f) {
    double t = m - (double)bb / ((double)gg * inv);
    t = fmin(fmax(t, -1e6), 1e6);
    Ai = 1;  Bi = (int)ceil(t);
  } else if (gg < 0.f) {
    double t = m - (double)bb / ((double)gg * inv);
    t = fmin(fmax(t, -1e6), 1e6);
    Ai = -1; Bi = -(int)floor(t);
  } else {
    Ai = 0;  Bi = (bb >= 0.f) ? 0 : 1;
  }
  A[c] = Ai; B[c] = Bi;
}

// NHWC int16 binarize (L0/L4/L5 path)
__global__ void binarize_k(const short* __restrict__ conv, int co, int H, int W, int pool,
                           uint32_t* __restrict__ out_bits, signed char* __restrict__ out8,
                           const int* __restrict__ A, const int* __restrict__ B,
                           float* __restrict__ hout) {
  __shared__ int As[256], Bs[256];
  int tid = threadIdx.x;
  for (int i = tid; i < co; i += 256) { As[i] = A[i]; Bs[i] = B[i]; }
  __syncthreads();

  int K32 = co >> 5;
  int Ho = pool ? (H >> 1) : H, Wo = pool ? (W >> 1) : W;
  int PH = Ho + 2, PW = Wo + 2;
  int total = BB * K32 * PH * PW;
  int idx = blockIdx.x * 256 + tid;
  if (idx >= total) return;
  int k  = idx % K32;
  int t1 = idx / K32;
  int px = t1 % PW; int t2 = t1 / PW;
  int py = t2 % PH; int b  = t2 / PH;
  uint32_t word = 0;
  if (py >= 1 && py <= Ho && px >= 1 && px <= Wo) {
    int oy = py - 1, ox = px - 1;
    int np = pool ? 2 : 1;
    for (int dy = 0; dy < np; ++dy)
      for (int dx = 0; dx < np; ++dx) {
        int iy = oy * np + dy, ix = ox * np + dx;
        const short* cp = conv + ((size_t)((b * H + iy) * W + ix)) * co + k * 32;
#pragma unroll
        for (int j = 0; j < 32; ++j) {
          int v = cp[j];
          int c = k * 32 + j;
          if (As[c] * v >= Bs[c]) word |= (1u << j);
        }
      }
    if (hout) {
#pragma unroll
      for (int j = 0; j < 32; ++j) {
        int c = k * 32 + j;
        hout[((size_t)(b * 128 + c) * 4 + oy) * 4 + ox] = ((word >> j) & 1) ? 1.f : -1.f;
      }
    }
  }
  if (out_bits)
    out_bits[((size_t)(b * K32 + k) * PH + py) * PW + px] = word;
  if (out8) {
    int dw[8];
#pragma unroll
    for (int jj = 0; jj < 8; ++jj) {
      uint32_t d = 0;
#pragma unroll
      for (int bb = 0; bb < 4; ++bb)
        d |= (((word >> (jj * 4 + bb)) & 1) ? 0x01u : 0xFFu) << (8 * bb);
      dw[jj] = (int)d;
    }
    signed char* p = out8 + (((size_t)(b * PH + py)) * PW + px) * (size_t)co + k * 32;
    *(i32x4*)p = *(i32x4*)&dw[0];
    *(i32x4*)(p + 16) = *(i32x4*)&dw[4];
  }
}

// ---------------- MFMA implicit-GEMM conv (counted-vmcnt ring pipeline) ----------------
// act: [B][H+2][W+2][CI] int8 (+-1, halo -1). wpk: fragment-packed weights (128-co half).
// Block: 4 waves (wm pixel-split, wn co-split); per wave: 2 px-tiles x 2 co-tiles.
// A-tile staged once in LDS (SWZA). B: 4-slot LDS ring, global_load_lds prefetch
// distance 3; per step: s_waitcnt vmcnt(2) + raw s_barrier (loads stay in flight
// across barriers -- never drain to 0 in the main loop; tail peeled vmcnt(1)/(0)).
// convout: fragment-native: ((swz*16 + fragLocal)*64 + lane)*16 + reg  (int16)
template <int CI, int W>
__global__ __launch_bounds__(256, 3) void conv_mfma_k(
    const signed char* __restrict__ act, const i32x4* __restrict__ wpk,
    short* __restrict__ convout, int* __restrict__ Sg, ull* __restrict__ SSg) {
  constexpr int KT = CI / 32;
  constexpr int PW = W + 2;
  constexpr int TR = 32 / W;           // rows per 32-px tile
  constexpr int ROWS_BLK = 4 * TR;
  constexpr int NBY = W / ROWS_BLK;
  constexpr int AROWS = ROWS_BLK + 2;
  constexpr int ABYTES = AROWS * PW * CI;
  constexpr int NSTEP = 9 * KT;        // 36 (L1) / 72 (L2,L3)

  __shared__ __attribute__((aligned(16))) char ldsA[ABYTES];
  __shared__ __attribute__((aligned(16))) char ldsB[4][4096];

  int nwg = gridDim.x;                 // divisible by 8
  int wg  = blockIdx.x;
  int swz = (wg & 7) * (nwg >> 3) + (wg >> 3);

  int tid = threadIdx.x;
  int b = swz / NBY, blk_y = swz % NBY;
  int y0 = blk_y * ROWS_BLK;

  int l = tid & 63, w = tid >> 6;
  int wm = w & 1, wn = w >> 1;
  int r = l & 31, khalf = l >> 5;
  int px = (TR == 1) ? r : (r & 15);

  // prologue: stage act tile into LDS (swizzled dest)
  const signed char* srcA = act + ((size_t)b * (W + 2) + y0) * PW * CI;
  for (int o = tid * 16; o < ABYTES; o += 4096) {
    i32x4 v = *(const i32x4*)(srcA + o);
    *(i32x4*)(ldsA + SWZA(o)) = v;
  }

  int inv[2];
#pragma unroll
  for (int m = 0; m < 2; ++m) {
    int ti = wm * 2 + m;
    int row = (TR == 1) ? ti : (ti * 2 + (r >> 4));
    inv[m] = (row * PW + px) * CI + khalf * 16;
  }

  // B staging: wave w stages fragment w of step s (1KB per wave, linear dest)
  typedef __attribute__((address_space(3))) char lds_c;
  typedef __attribute__((address_space(1))) const char g_c;
  auto STAGE_B = [&](int s, int slot) {
    int t = s / KT, kt = s % KT;
    const signed char* srcB = (const signed char*)(wpk + (size_t)((w * 9 + t) * KT + kt) * 64 + l);
    __builtin_amdgcn_global_load_lds((const g_c*)srcB, (lds_c*)&ldsB[slot][w * 1024], 16, 0, 0);
  };

  i32x16 acc[2][2];
#pragma unroll
  for (int m = 0; m < 2; ++m)
#pragma unroll
    for (int n = 0; n < 2; ++n)
#pragma unroll
      for (int q = 0; q < 16; ++q) acc[m][n][q] = 0;

  STAGE_B(0, 0);
  STAGE_B(1, 1);
  STAGE_B(2, 2);
  __syncthreads();   // drains A-stage + prologue B stages (one-time cost)

#define CSTEP(S, VMSTR)                                                          \
  {                                                                              \
    asm volatile("s_waitcnt vmcnt(" VMSTR ")" ::: "memory");                     \
    __builtin_amdgcn_s_barrier();                                                \
    __builtin_amdgcn_sched_barrier(0);                                           \
    int s_ = (S);                                                                \
    if (s_ + 3 < NSTEP) STAGE_B(s_ + 3, (s_ + 3) & 3);                           \
    int t_ = s_ / KT, kt_ = s_ % KT;                                             \
    int soff_ = ((t_ / 3) * PW + (t_ % 3)) * CI + kt_ * 32;                      \
    i32x4 a0_, a1_, b0_, b1_;                                                    \
    { int o_ = SWZA(inv[0] + soff_); a0_ = *(const i32x4*)(ldsA + o_); }         \
    { int o_ = SWZA(inv[1] + soff_); a1_ = *(const i32x4*)(ldsA + o_); }         \
    int sl_ = s_ & 3;                                                            \
    b0_ = *(const i32x4*)&ldsB[sl_][(wn * 2 + 0) * 1024 + l * 16];               \
    b1_ = *(const i32x4*)&ldsB[sl_][(wn * 2 + 1) * 1024 + l * 16];               \
    acc[0][0] = __builtin_amdgcn_mfma_i32_32x32x32_i8(a0_, b0_, acc[0][0], 0, 0, 0); \
    acc[0][1] = __builtin_amdgcn_mfma_i32_32x32x32_i8(a0_, b1_, acc[0][1], 0, 0, 0); \
    acc[1][0] = __builtin_amdgcn_mfma_i32_32x32x32_i8(a1_, b0_, acc[1][0], 0, 0, 0); \
    acc[1][1] = __builtin_amdgcn_mfma_i32_32x32x32_i8(a1_, b1_, acc[1][1], 0, 0, 0); \
  }

#pragma unroll 4
  for (int s = 0; s < NSTEP - 2; ++s) CSTEP(s, "2");
  CSTEP(NSTEP - 2, "1");
  CSTEP(NSTEP - 1, "0");
#undef CSTEP

  // epilogue: frag-native int16 store + per-channel integer stats
#pragma unroll
  for (int n = 0; n < 2; ++n) {
    int s1 = 0, s2 = 0;
#pragma unroll
    for (int m = 0; m < 2; ++m) {
      int ti = wm * 2 + m;
      i32x16 v = acc[m][n];
      int pk[8];
#pragma unroll
      for (int q = 0; q < 8; ++q) {
        int v0 = v[2 * q], v1 = v[2 * q + 1];
        s1 += v0 + v1; s2 += v0 * v0 + v1 * v1;
        pk[q] = (v0 & 0xffff) | (v1 << 16);
      }
      int fragLocal = ti * 4 + wn * 2 + n;
      size_t baseS = (((size_t)swz * 16 + fragLocal) * 64 + l) * 16;
      *(i32x4*)(convout + baseS) = *(i32x4*)&pk[0];
      *(i32x4*)(convout + baseS + 8) = *(i32x4*)&pk[4];
    }
    s1 += __shfl_xor(s1, 32);
    s2 += __shfl_xor(s2, 32);
    if (l < 32) {
      int ch = wn * 64 + n * 32 + l;
      atomicAdd(&Sg[ch], s1);
      atomicAdd(&SSg[ch], (ull)(long long)s2);
    }
  }
}

// ---------------- fragment-layout binarize (same XCD swizzle as conv) ----------------
template <int CO_BLK, int W, int POOL, int OUT_BITS, int OUTP, int K32TOT>
__global__ __launch_bounds__(256) void binarize_frag_k(
    const short* __restrict__ convout, signed char* __restrict__ out8,
    uint32_t* __restrict__ out_bits, const int* __restrict__ Ath,
    const int* __restrict__ Bth, int co_base) {
  constexpr int TR = 32 / W;
  constexpr int ROWS_BLK = 4 * TR;
  constexpr int NBY = W / ROWS_BLK;
  constexpr int K32B = CO_BLK / 32;
  constexpr int NT = CO_BLK / 64;
  constexpr int Wout = POOL ? W / 2 : W;
  constexpr int HoutB = POOL ? ROWS_BLK / 2 : ROWS_BLK;
  constexpr int WORDS = HoutB * Wout * K32B;
  constexpr int NP = POOL ? 2 : 1;
  constexpr int LBYTES = 128 * CO_BLK * 2;

  __shared__ __attribute__((aligned(16))) char ldsC[LBYTES];
  int tid = threadIdx.x;
  int nwg = gridDim.x;
  int wg  = blockIdx.x;
  int swz = (wg & 7) * (nwg >> 3) + (wg >> 3);   // match conv
  int b = swz / NBY, blk_y = swz % NBY;

  const char* src = (const char*)(convout + (size_t)swz * (128 * CO_BLK));
  for (int o = tid * 16; o < LBYTES; o += 4096) {
    i32x4 v = *(const i32x4*)(src + o);
    int so = o ^ (((o >> 11) & 7) << 4);
    *(i32x4*)(ldsC + so) = v;
  }
  __syncthreads();

  for (int widx = tid; widx < WORDS; widx += 256) {
    int k = widx % K32B, opx = widx / K32B;
    int oy = opx / Wout, ox = opx % Wout;
    int wn = k / NT, n = k % NT;
    int bases[NP * NP];
#pragma unroll
    for (int dy = 0; dy < NP; ++dy)
#pragma unroll
      for (int dx = 0; dx < NP; ++dx) {
        int yl = POOL ? oy * 2 + dy : oy;
        int x  = POOL ? ox * 2 + dx : ox;
        int ti = yl / TR;
        int rr = (TR == 1) ? x : ((yl & 1) * 16 + x);
        int hi = (rr >> 2) & 1, q = (rr & 3) + 4 * (rr >> 3);
        int fragLocal = ti * K32B + wn * NT + n;
        bases[dy * NP + dx] = ((fragLocal * 64 + hi * 32) * 16 + q) * 2;
      }
    uint32_t word = 0;
    for (int j = 0; j < 32; ++j) {
      int c = k * 32 + j;
      int Aj = Ath[c], Bj = Bth[c];
      int mx = -0x7fffffff;
#pragma unroll
      for (int p2 = 0; p2 < NP * NP; ++p2) {
        int bo = bases[p2] + j * 32;
        bo ^= ((bo >> 11) & 7) << 4;
        int v = *(const short*)(ldsC + bo);
        int av = Aj * v;
        mx = (av > mx) ? av : mx;
      }
      if (mx >= Bj) word |= (1u << j);
    }
    int gy = blk_y * HoutB + oy, gx = ox;
    if (OUT_BITS) {
      out_bits[(((size_t)b * K32TOT + (co_base >> 5) + k) * OUTP + 1 + gy) * OUTP + 1 + gx] = word;
    } else {
      size_t a0 = (((size_t)b * OUTP + (1 + gy)) * OUTP + (1 + gx)) * 256 + co_base + k * 32;
      int dw[8];
#pragma unroll
      for (int jj = 0; jj < 8; ++jj) {
        uint32_t d = 0;
#pragma unroll
        for (int bb = 0; bb < 4; ++bb)
          d |= (((word >> (jj * 4 + bb)) & 1) ? 0x01u : 0xFFu) << (8 * bb);
        dw[jj] = (int)d;
      }
      *(i32x4*)(out8 + a0) = *(i32x4*)&dw[0];
      *(i32x4*)(out8 + a0 + 16) = *(i32x4*)&dw[4];
    }
  }
}

// ---------------- popcount conv (L4/L5) ----------------
template <int K32>
__global__ void __launch_bounds__(256) conv_xnor_k(
    const uint32_t* __restrict__ act, const uint32_t* __restrict__ wb,
    short* __restrict__ convout, int* __restrict__ Sg, ull* __restrict__ SSg,
    int co, int H, int Ktot) {
  int Hp  = H + 2;
  int T   = H >> 3;
  int cot = co >> 6;
  int TT  = T * T * cot;
  int b   = blockIdx.x / TT;
  int r   = blockIdx.x % TT;
  int ct  = r % cot;
  int tt  = r / cot;
  int ty  = tt / T, tx = tt % T;
  int co_base = ct << 6;

  __shared__ __attribute__((aligned(16))) uint32_t ldsA[K32 * 10 * 12];
  __shared__ __attribute__((aligned(16))) uint32_t ldsB[9 * K32 * 64];
  __shared__ int sS[64];
  __shared__ int sSS[64];

  int tid = threadIdx.x;
  if (tid < 64) { sS[tid] = 0; sSS[tid] = 0; }
  for (int i = tid; i < 9 * K32 * 64; i += 256) {
    int c  = i & 63;
    int tk = i >> 6;
    ldsB[i] = wb[(size_t)tk * co + co_base + c];
  }
  const uint32_t* ab = act + (size_t)b * K32 * Hp * Hp;
  for (int i = tid; i < K32 * 100; i += 256) {
    int k  = i / 100;
    int rr = i % 100;
    int yy = rr / 10, xx = rr % 10;
    ldsA[(k * 10 + yy) * 12 + xx] = ab[(size_t)(k * Hp + ty * 8 + yy) * Hp + tx * 8 + xx];
  }
  __syncthreads();

  int tc   = tid & 15;
  int pgp  = tid >> 4;
  int yrow = pgp >> 1;
  int xg   = pgp & 1;

  int acc[4][4];
#pragma unroll
  for (int i = 0; i < 4; ++i)
#pragma unroll
    for (int j = 0; j < 4; ++j) acc[i][j] = 0;

#pragma unroll 1
  for (int k = 0; k < K32; ++k) {
#pragma unroll
    for (int kh = 0; kh < 3; ++kh) {
      int abase = (k * 10 + yrow + kh) * 12 + xg * 4;
      uint4 a0 = *(const uint4*)&ldsA[abase];
      uint2 a1 = *(const uint2*)&ldsA[abase + 4];
      uint32_t arow[6] = {a0.x, a0.y, a0.z, a0.w, a1.x, a1.y};
#pragma unroll
      for (int kw = 0; kw < 3; ++kw) {
        int t = kh * 3 + kw;
        uint4 bwv = *(const uint4*)&ldsB[(t * K32 + k) * 64 + tc * 4];
        uint32_t bwa[4] = {bwv.x, bwv.y, bwv.z, bwv.w};
#pragma unroll
        for (int pi = 0; pi < 4; ++pi) {
          uint32_t aw = arow[pi + kw];
#pragma unroll
          for (int cj = 0; cj < 4; ++cj)
            acc[pi][cj] += __popc(aw ^ bwa[cj]);
        }
      }
    }
  }

  int vS[4] = {0, 0, 0, 0}, vSS[4] = {0, 0, 0, 0};
  int gy0 = ty * 8 + yrow, gx0 = tx * 8 + xg * 4;
#pragma unroll
  for (int pi = 0; pi < 4; ++pi) {
    short4 vv;
    int v0 = Ktot - 2 * acc[pi][0];
    int v1 = Ktot - 2 * acc[pi][1];
    int v2 = Ktot - 2 * acc[pi][2];
    int v3 = Ktot - 2 * acc[pi][3];
    vS[0] += v0; vSS[0] += v0 * v0;
    vS[1] += v1; vSS[1] += v1 * v1;
    vS[2] += v2; vSS[2] += v2 * v2;
    vS[3] += v3; vSS[3] += v3 * v3;
    vv.x = (short)v0; vv.y = (short)v1; vv.z = (short)v2; vv.w = (short)v3;
    size_t obase = ((size_t)(b * H + gy0) * H + (gx0 + pi)) * co + co_base + tc * 4;
    *(short4*)&convout[obase] = vv;
  }
#pragma unroll
  for (int cj = 0; cj < 4; ++cj) {
    atomicAdd(&sS[tc * 4 + cj], vS[cj]);
    atomicAdd(&sSS[tc * 4 + cj], vSS[cj]);
  }
  __syncthreads();
  if (tid < 64) {
    atomicAdd(&Sg[co_base + tid], sS[tid]);
    atomicAdd(&SSg[co_base + tid], (ull)(long long)sSS[tid]);
  }
}

__global__ void fc_k(const float* __restrict__ h, const float* __restrict__ fcw,
                     const float* __restrict__ fcb, float* __restrict__ out) {
  int b = blockIdx.x;
  int tid = threadIdx.x;
  int j = tid & 15;
  int chunk = tid >> 4;
  __shared__ float red[16][17];
  float acc = 0.f;
  if (j < 10) {
    const float* hp = h + (size_t)b * 2048 + chunk * 128;
    const float* wp = fcw + (size_t)j * 2048 + chunk * 128;
    for (int i = 0; i < 128; ++i) acc += hp[i] * wp[i];
  }
  red[chunk][j] = acc;
  __syncthreads();
  if (tid < 10) {
    float s = fcb[tid];
    for (int c = 0; c < 16; ++c) s += red[c][tid];
    out[b * 10 + tid] = s;
  }
}

// ---------------- launch ----------------

extern "C" void kernel_launch(void* const* d_in, const int* in_sizes, int n_in,
                              void* d_out, int out_size, void* d_ws, size_t ws_size,
                              hipStream_t stream) {
  (void)in_sizes; (void)n_in; (void)out_size;
  if (ws_size < WS_NEEDED) return;

  const float* x = (const float*)d_in[0];
  const float* w[6]; const float* g[6]; const float* bt[6];
  for (int i = 0; i < 6; ++i) {
    w[i]  = (const float*)d_in[1 + 3 * i];
    g[i]  = (const float*)d_in[2 + 3 * i];
    bt[i] = (const float*)d_in[3 + 3 * i];
  }
  const float* fcw = (const float*)d_in[19];
  const float* fcb = (const float*)d_in[20];

  char* ws = (char*)d_ws;
  short*        convout = (short*)(ws + OFF_CONV);
  signed char*  act1    = (signed char*)(ws + OFF_ACT1);
  signed char*  act2    = (signed char*)(ws + OFF_ACT2);
  uint32_t*     bits4   = (uint32_t*)(ws + OFF_BITS4);
  uint32_t*     bits5   = (uint32_t*)(ws + OFF_BITS5);
  uint32_t*     wbpc    = (uint32_t*)(ws + OFF_WBPC);
  signed char*  wpkc    = (signed char*)(ws + OFF_WPK);
  int*          Sg      = (int*)(ws + OFF_S);
  ull*          SSg     = (ull*)(ws + OFF_SS);
  int*          Athr    = (int*)(ws + OFF_ATHR);
  int*          Bthr    = (int*)(ws + OFF_BTHR);
  float*        hbuf    = (float*)(ws + OFF_H);
  uint32_t*     xbits   = (uint32_t*)(ws + OFF_XB);
  uint32_t*     w27     = xbits + 24576;
  float*        out     = (float*)d_out;

  const i32x4* wpk1 = (const i32x4*)wpkc;            // L1: 2 halves of 9216 frags
  const i32x4* wpk2 = wpk1 + 294912 / 16;            // L2: 2 halves of 18432
  const i32x4* wpk3 = wpk1 + 884736 / 16;            // L3

  zero_stats_k<<<6, 256, 0, stream>>>(Sg, SSg);

  pack_w_k<<<36, 256, 0, stream>>>(w[4], wbpc, 128, 256);
  pack_w_k<<<18, 256, 0, stream>>>(w[5], wbpc + 9216, 128, 128);
  pack_wmfma_k<<<72, 256, 0, stream>>>(w[1], wpkc, 256, 128);
  pack_wmfma_k<<<144, 256, 0, stream>>>(w[2], wpkc + 294912, 256, 256);
  pack_wmfma_k<<<144, 256, 0, stream>>>(w[3], wpkc + 884736, 256, 256);
  pack_x_k<<<96, 256, 0, stream>>>(x, xbits);
  pack_w0_k<<<1, 128, 0, stream>>>(w[0], w27);

  hipMemsetAsync(act2, 0xFF, 21233664, stream);   // L2-in halo
  hipMemsetAsync(bits4, 0x00, 819200, stream);    // L4-in halo

  // ---- L0: popcount conv (ci=3), int8-NHWC binarize -> act1 ----
  conv0x_k<<<256 * 4, 256, 0, stream>>>(xbits, w27, convout, Sg, SSg);
  finalize_k<<<1, 256, 0, stream>>>(Sg, SSg, Athr, Bthr, g[0], bt[0], 128, 262144);
  binarize_k<<<(256 * 4 * 34 * 34 + 255) / 256, 256, 0, stream>>>(
      convout, 128, 32, 32, 0, nullptr, act1, Athr, Bthr, nullptr);

  // ---- L1: MFMA conv, two co-halves (ci=128, co=256, H=32, pool) -> act2 ----
  conv_mfma_k<128, 32><<<2048, 256, 0, stream>>>(act1, wpk1, convout, Sg + 256, SSg + 256);
  finalize_k<<<1, 256, 0, stream>>>(Sg + 256, SSg + 256, Athr + 256, Bthr + 256, g[1], bt[1], 128, 262144);
  binarize_frag_k<128, 32, 1, 0, 18, 8><<<2048, 256, 0, stream>>>(
      convout, act2, nullptr, Athr + 256, Bthr + 256, 0);

  conv_mfma_k<128, 32><<<2048, 256, 0, stream>>>(act1, wpk1 + 9216, convout, Sg + 384, SSg + 384);
  finalize_k<<<1, 256, 0, stream>>>(Sg + 384, SSg + 384, Athr + 384, Bthr + 384, g[1] + 128, bt[1] + 128, 128, 262144);
  hipMemsetAsync(act1, 0xFF, 21233664, stream);   // L3-in halo (act1 L0-content dead now)
  binarize_frag_k<128, 32, 1, 0, 18, 8><<<2048, 256, 0, stream>>>(
      convout, act2, nullptr, Athr + 384, Bthr + 384, 128);

  // ---- L2: MFMA conv, two co-halves (ci=256, co=256, H=16, no pool) -> act1 ----
  conv_mfma_k<256, 16><<<512, 256, 0, stream>>>(act2, wpk2, convout, Sg + 512, SSg + 512);
  finalize_k<<<1, 256, 0, stream>>>(Sg + 512, SSg + 512, Athr + 512, Bthr + 512, g[2], bt[2], 128, 65536);
  binarize_frag_k<128, 16, 0, 0, 18, 8><<<512, 256, 0, stream>>>(
      convout, act1, nullptr, Athr + 512, Bthr + 512, 0);

  conv_mfma_k<256, 16><<<512, 256, 0, stream>>>(act2, wpk2 + 18432, convout, Sg + 640, SSg + 640);
  finalize_k<<<1, 256, 0, stream>>>(Sg + 640, SSg + 640, Athr + 640, Bthr + 640, g[2] + 128, bt[2] + 128, 128, 65536);
  binarize_frag_k<128, 16, 0, 0, 18, 8><<<512, 256, 0, stream>>>(
      convout, act1, nullptr, Athr + 640, Bthr + 640, 128);

  // ---- L3: MFMA conv, two co-halves (ci=256, co=256, H=16, pool) -> bits4 ----
  conv_mfma_k<256, 16><<<512, 256, 0, stream>>>(act1, wpk3, convout, Sg + 768, SSg + 768);
  finalize_k<<<1, 256, 0, stream>>>(Sg + 768, SSg + 768, Athr + 768, Bthr + 768, g[3], bt[3], 128, 65536);
  binarize_frag_k<128, 16, 1, 1, 10, 8><<<512, 256, 0, stream>>>(
      convout, nullptr, bits4, Athr + 768, Bthr + 768, 0);

  conv_mfma_k<256, 16><<<512, 256, 0, stream>>>(act1, wpk3 + 18432, convout, Sg + 896, SSg + 896);
  finalize_k<<<1, 256, 0, stream>>>(Sg + 896, SSg + 896, Athr + 896, Bthr + 896, g[3] + 128, bt[3] + 128, 128, 65536);
  binarize_frag_k<128, 16, 1, 1, 10, 8><<<512, 256, 0, stream>>>(
      convout, nullptr, bits4, Athr + 896, Bthr + 896, 128);

  // ---- L4: popcount conv (ci=256, co=128, H=8, no pool) ----
  conv_xnor_k<8><<<256 * 2, 256, 0, stream>>>(bits4, wbpc, convout,
                                              Sg + 1024, SSg + 1024, 128, 8, 2304);
  finalize_k<<<1, 256, 0, stream>>>(Sg + 1024, SSg + 1024, Athr + 1024, Bthr + 1024, g[4], bt[4], 128, 16384);
  binarize_k<<<(256 * 4 * 10 * 10 + 255) / 256, 256, 0, stream>>>(
      convout, 128, 8, 8, 0, bits5, nullptr, Athr + 1024, Bthr + 1024, nullptr);

  // ---- L5: popcount conv (ci=128, co=128, H=8, pool) -> hbuf ----
  conv_xnor_k<4><<<256 * 2, 256, 0, stream>>>(bits5, wbpc + 9216, convout,
                                              Sg + 1280, SSg + 1280, 128, 8, 1152);
  finalize_k<<<1, 256, 0, stream>>>(Sg + 1280, SSg + 1280, Athr + 1280, Bthr + 1280, g[5], bt[5], 128, 16384);
  binarize_k<<<(256 * 4 * 6 * 6 + 255) / 256, 256, 0, stream>>>(
      convout, 128, 8, 8, 1, bits4, nullptr, Athr + 1280, Bthr + 1280, hbuf);

  fc_k<<<256, 256, 0, stream>>>(hbuf, fcw, fcb, out);
}

// Round 10
// 575.698 us; speedup vs baseline: 1.3499x; 1.3499x over previous
//
#include <hip/hip_runtime.h>
#include <stdint.h>

typedef unsigned long long ull;
#define BB 256

// ---------------- workspace layout (bytes) ----------------
static const size_t OFF_CONV  = 0;              // 134217728  int16 convout (max L1: 256*32*32*256)
static const size_t OFF_BITSA = 134217728;      // 256*4*34*34*4 = 4734976
static const size_t OFF_BITSB = 138952704;      // 256*8*18*18*4 = 2654208
static const size_t OFF_WB    = 141606912;      // 59904 words = 239616
static const size_t OFF_S     = 141846528;      // 6*256*4
static const size_t OFF_SS    = 141852672;      // 6*256*8
static const size_t OFF_ATHR  = 141864960;      // 6*256*4
static const size_t OFF_BTHR  = 141877248;      // 6*256*4
static const size_t OFF_H     = 141889536;      // 256*2048*4
static const size_t WS_NEEDED = 143986688;
// xbits+w27 live in the UNUSED upper part of the conv region during L0
static const size_t OFF_XBITS = 100 * 1024 * 1024;

// ---------------- kernels ----------------

__global__ void zero_stats_k(int* __restrict__ S, ull* __restrict__ SS) {
  int i = blockIdx.x * blockDim.x + threadIdx.x;
  if (i < 6 * 256) { S[i] = 0; SS[i] = 0ull; }
}

// pack sign bits of w[co][ci][3][3] into out[(t*K32+k)*co + c], bit j = sign(w[c][k*32+j][t])
__global__ void pack_w_k(const float* __restrict__ w, uint32_t* __restrict__ out,
                         int co, int ci) {
  int K32 = ci >> 5;
  int total = 9 * K32 * co;
  int idx = blockIdx.x * blockDim.x + threadIdx.x;
  if (idx >= total) return;
  int c  = idx % co;
  int tk = idx / co;
  int k  = tk % K32;
  int t  = tk / K32;      // t = kh*3+kw
  uint32_t word = 0;
  const float* wc = w + (size_t)c * ci * 9 + t;
  for (int j = 0; j < 32; ++j)
    if (wc[(size_t)(k * 32 + j) * 9] >= 0.f) word |= (1u << j);
  out[idx] = word;
}

// pack input x (+-1) into bitplane rows: xbits[(b*3+c)*32+y], bit xx = (x>=0)
__global__ void pack_x_k(const float* __restrict__ x, uint32_t* __restrict__ xbits) {
  int idx = blockIdx.x * 256 + threadIdx.x;   // < 256*3*32 = 24576
  if (idx >= 24576) return;
  const float* xp = x + (size_t)idx * 32;
  uint32_t w = 0;
#pragma unroll
  for (int j = 0; j < 32; ++j) if (xp[j] >= 0.f) w |= (1u << j);
  xbits[idx] = w;
}

// pack w0[co][3][3][3] (co=128, ci=3) into 27-bit words, bit t=c*9+kh*3+kw
__global__ void pack_w0_k(const float* __restrict__ w0, uint32_t* __restrict__ w27) {
  int co = threadIdx.x;  // 128
  uint32_t w = 0;
#pragma unroll
  for (int t = 0; t < 27; ++t) if (w0[co * 27 + t] >= 0.f) w |= (1u << t);
  w27[co] = w;
}

// layer 0 conv via 27-bit popcount. Block: (batch b, row-group rg of 8 rows).
// 256 threads: phase1 builds 256 a27 words; phase2: thread (co=tid&127, half) does 128 pixels.
__global__ void __launch_bounds__(256) conv0x_k(
    const uint32_t* __restrict__ xbits, const uint32_t* __restrict__ w27,
    short* __restrict__ convout, int* __restrict__ Sg, ull* __restrict__ SSg) {
  int b  = blockIdx.x >> 2;
  int rg = blockIdx.x & 3;
  __shared__ uint32_t a27s[256];
  __shared__ uint32_t wlds[128];
  __shared__ int sS[256], sSS[256];
  int tid = threadIdx.x;
  if (tid < 128) wlds[tid] = w27[tid];

  int p = rg * 256 + tid;
  int y = p >> 5, xx = p & 31;
  const uint32_t* xb = xbits + (size_t)b * 96;
  uint32_t a27 = 0;
#pragma unroll
  for (int c = 0; c < 3; ++c)
#pragma unroll
    for (int kh = 0; kh < 3; ++kh) {
      int iy = y + kh - 1;
      uint32_t r = (iy >= 0 && iy < 32) ? xb[c * 32 + iy] : 0u;
      uint32_t bits3 = (uint32_t)((((uint64_t)r) << 1) >> xx) & 7u;
      a27 |= bits3 << (c * 9 + kh * 3);
    }
  a27s[tid] = a27;
  __syncthreads();

  int co = tid & 127, half = tid >> 7;
  uint32_t wv = wlds[co];
  int S = 0, SS = 0;
  int base = rg * 256 + half * 128;
  short* cb = convout + ((size_t)b * 1024 + base) * 128 + co;
  for (int i = 0; i < 128; ++i) {
    uint32_t a = a27s[half * 128 + i];
    int v = 27 - 2 * __popc(a ^ wv);
    S += v; SS += v * v;
    cb[(size_t)i * 128] = (short)v;
  }
  sS[tid] = S; sSS[tid] = SS;
  __syncthreads();
  if (tid < 128) {
    atomicAdd(&Sg[tid], sS[tid] + sS[tid + 128]);
    atomicAdd(&SSg[tid], (ull)(long long)(sSS[tid] + sSS[tid + 128]));
  }
}

// per-channel integer threshold: bit = (A*v >= B)
// gamma>0: v >= ceil(t);  gamma<0: v <= floor(t) (encoded -v >= -floor(t));  gamma==0: const
__global__ void finalize_k(const int* __restrict__ S, const ull* __restrict__ SS,
                           int* __restrict__ A, int* __restrict__ B,
                           const float* __restrict__ gamma, const float* __restrict__ beta,
                           int co, int N) {
  int c = threadIdx.x;
  if (c >= co) return;
  double m  = (double)S[c] / (double)N;
  double e2 = (double)SS[c] / (double)N;
  double inv = 1.0 / sqrt(e2 - m * m + 1e-5);
  float gg = gamma[c], bb = beta[c];
  int Ai, Bi;
  if (gg > 0.f) {
    double t = m - (double)bb / ((double)gg * inv);
    t = fmin(fmax(t, -1e6), 1e6);
    Ai = 1;  Bi = (int)ceil(t);
  } else if (gg < 0.f) {
    double t = m - (double)bb / ((double)gg * inv);
    t = fmin(fmax(t, -1e6), 1e6);
    Ai = -1; Bi = -(int)floor(t);
  } else {
    Ai = 0;  Bi = (bb >= 0.f) ? 0 : 1;
  }
  A[c] = Ai; B[c] = Bi;
}

// BN sign (integer threshold) + optional 2x2 maxpool (OR of bits) + pack into padded bitplanes
// out layout: [B][K32][Ho+2][Wo+2] words (halo = 0 == -1)
__global__ void binarize_k(const short* __restrict__ conv, int co, int H, int W, int pool,
                           uint32_t* __restrict__ out, const int* __restrict__ A,
                           const int* __restrict__ B, float* __restrict__ hout) {
  __shared__ int As[256], Bs[256];
  int tid = threadIdx.x;
  for (int i = tid; i < co; i += 256) { As[i] = A[i]; Bs[i] = B[i]; }
  __syncthreads();

  int K32 = co >> 5;
  int Ho = pool ? (H >> 1) : H, Wo = pool ? (W >> 1) : W;
  int PH = Ho + 2, PW = Wo + 2;
  int total = BB * K32 * PH * PW;
  int idx = blockIdx.x * 256 + tid;
  if (idx >= total) return;
  int k  = idx % K32;
  int t1 = idx / K32;
  int px = t1 % PW; int t2 = t1 / PW;
  int py = t2 % PH; int b  = t2 / PH;
  uint32_t word = 0;
  if (py >= 1 && py <= Ho && px >= 1 && px <= Wo) {
    int oy = py - 1, ox = px - 1;
    int np = pool ? 2 : 1;
    for (int dy = 0; dy < np; ++dy)
      for (int dx = 0; dx < np; ++dx) {
        int iy = oy * np + dy, ix = ox * np + dx;
        const short* cp = conv + ((size_t)((b * H + iy) * W + ix)) * co + k * 32;
#pragma unroll
        for (int j = 0; j < 32; ++j) {
          int v = cp[j];
          int c = k * 32 + j;
          if (As[c] * v >= Bs[c]) word |= (1u << j);
        }
      }
    if (hout) {   // last layer: emit float +-1 in NCHW for the FC
#pragma unroll
      for (int j = 0; j < 32; ++j) {
        int c = k * 32 + j;
        hout[((size_t)(b * 128 + c) * 4 + oy) * 4 + ox] = ((word >> j) & 1) ? 1.f : -1.f;
      }
    }
  }
  out[((size_t)(b * K32 + k) * PH + py) * PW + px] = word;
}

// XNOR-popcount conv. act: [B][K32][H+2][H+2] words, wb: [9][K32][co] words.
// Block: 256 threads -> 64 pixels (8x8 tile) x 64 co, 4x4 per thread.
template <int K32>
__global__ void __launch_bounds__(256) conv_xnor_k(
    const uint32_t* __restrict__ act, const uint32_t* __restrict__ wb,
    short* __restrict__ convout, int* __restrict__ Sg, ull* __restrict__ SSg,
    int co, int H, int Ktot) {
  int Hp  = H + 2;
  int T   = H >> 3;
  int cot = co >> 6;
  int TT  = T * T * cot;
  int b   = blockIdx.x / TT;
  int r   = blockIdx.x % TT;
  int ct  = r % cot;
  int tt  = r / cot;
  int ty  = tt / T, tx = tt % T;
  int co_base = ct << 6;

  __shared__ __attribute__((aligned(16))) uint32_t ldsA[K32 * 10 * 12];
  __shared__ __attribute__((aligned(16))) uint32_t ldsB[9 * K32 * 64];
  __shared__ int sS[64];
  __shared__ int sSS[64];

  int tid = threadIdx.x;
  if (tid < 64) { sS[tid] = 0; sSS[tid] = 0; }
  for (int i = tid; i < 9 * K32 * 64; i += 256) {
    int c  = i & 63;
    int tk = i >> 6;
    ldsB[i] = wb[(size_t)tk * co + co_base + c];
  }
  const uint32_t* ab = act + (size_t)b * K32 * Hp * Hp;
  for (int i = tid; i < K32 * 100; i += 256) {
    int k  = i / 100;
    int rr = i % 100;
    int yy = rr / 10, xx = rr % 10;
    ldsA[(k * 10 + yy) * 12 + xx] = ab[(size_t)(k * Hp + ty * 8 + yy) * Hp + tx * 8 + xx];
  }
  __syncthreads();

  int tc   = tid & 15;    // 4-co group
  int pgp  = tid >> 4;    // 16 pixel groups
  int yrow = pgp >> 1;
  int xg   = pgp & 1;

  int acc[4][4];
#pragma unroll
  for (int i = 0; i < 4; ++i)
#pragma unroll
    for (int j = 0; j < 4; ++j) acc[i][j] = 0;

#pragma unroll 1
  for (int k = 0; k < K32; ++k) {
#pragma unroll
    for (int kh = 0; kh < 3; ++kh) {
      int abase = (k * 10 + yrow + kh) * 12 + xg * 4;
      uint4 a0 = *(const uint4*)&ldsA[abase];
      uint2 a1 = *(const uint2*)&ldsA[abase + 4];
      uint32_t arow[6] = {a0.x, a0.y, a0.z, a0.w, a1.x, a1.y};
#pragma unroll
      for (int kw = 0; kw < 3; ++kw) {
        int t = kh * 3 + kw;
        uint4 bwv = *(const uint4*)&ldsB[(t * K32 + k) * 64 + tc * 4];
        uint32_t bwa[4] = {bwv.x, bwv.y, bwv.z, bwv.w};
#pragma unroll
        for (int pi = 0; pi < 4; ++pi) {
          uint32_t aw = arow[pi + kw];
#pragma unroll
          for (int cj = 0; cj < 4; ++cj)
            acc[pi][cj] += __popc(aw ^ bwa[cj]);
        }
      }
    }
  }

  int vS[4] = {0, 0, 0, 0}, vSS[4] = {0, 0, 0, 0};
  int gy0 = ty * 8 + yrow, gx0 = tx * 8 + xg * 4;
#pragma unroll
  for (int pi = 0; pi < 4; ++pi) {
    short4 vv;
    int v0 = Ktot - 2 * acc[pi][0];
    int v1 = Ktot - 2 * acc[pi][1];
    int v2 = Ktot - 2 * acc[pi][2];
    int v3 = Ktot - 2 * acc[pi][3];
    vS[0] += v0; vSS[0] += v0 * v0;
    vS[1] += v1; vSS[1] += v1 * v1;
    vS[2] += v2; vSS[2] += v2 * v2;
    vS[3] += v3; vSS[3] += v3 * v3;
    vv.x = (short)v0; vv.y = (short)v1; vv.z = (short)v2; vv.w = (short)v3;
    size_t obase = ((size_t)(b * H + gy0) * H + (gx0 + pi)) * co + co_base + tc * 4;
    *(short4*)&convout[obase] = vv;
  }
#pragma unroll
  for (int cj = 0; cj < 4; ++cj) {
    atomicAdd(&sS[tc * 4 + cj], vS[cj]);
    atomicAdd(&sSS[tc * 4 + cj], vSS[cj]);
  }
  __syncthreads();
  if (tid < 64) {
    atomicAdd(&Sg[co_base + tid], sS[tid]);
    atomicAdd(&SSg[co_base + tid], (ull)(long long)sSS[tid]);
  }
}

// FC: out[b][j] = sum_k h[b][k]*w[j][k] + bias[j]; h in {-1,+1}
__global__ void fc_k(const float* __restrict__ h, const float* __restrict__ fcw,
                     const float* __restrict__ fcb, float* __restrict__ out) {
  int b = blockIdx.x;
  int tid = threadIdx.x;
  int j = tid & 15;
  int chunk = tid >> 4;
  __shared__ float red[16][17];
  float acc = 0.f;
  if (j < 10) {
    const float* hp = h + (size_t)b * 2048 + chunk * 128;
    const float* wp = fcw + (size_t)j * 2048 + chunk * 128;
    for (int i = 0; i < 128; ++i) acc += hp[i] * wp[i];
  }
  red[chunk][j] = acc;
  __syncthreads();
  if (tid < 10) {
    float s = fcb[tid];
    for (int c = 0; c < 16; ++c) s += red[c][tid];
    out[b * 10 + tid] = s;
  }
}

// ---------------- launch ----------------

extern "C" void kernel_launch(void* const* d_in, const int* in_sizes, int n_in,
                              void* d_out, int out_size, void* d_ws, size_t ws_size,
                              hipStream_t stream) {
  (void)in_sizes; (void)n_in; (void)out_size;
  if (ws_size < WS_NEEDED) return;  // fail visibly rather than corrupt memory

  const float* x = (const float*)d_in[0];
  const float* w[6]; const float* g[6]; const float* bt[6];
  for (int i = 0; i < 6; ++i) {
    w[i]  = (const float*)d_in[1 + 3 * i];
    g[i]  = (const float*)d_in[2 + 3 * i];
    bt[i] = (const float*)d_in[3 + 3 * i];
  }
  const float* fcw = (const float*)d_in[19];
  const float* fcb = (const float*)d_in[20];

  char* ws = (char*)d_ws;
  short*     convout = (short*)(ws + OFF_CONV);
  uint32_t*  bitsA   = (uint32_t*)(ws + OFF_BITSA);
  uint32_t*  bitsB   = (uint32_t*)(ws + OFF_BITSB);
  uint32_t*  wbits   = (uint32_t*)(ws + OFF_WB);
  int*       Sg      = (int*)(ws + OFF_S);
  ull*       SSg     = (ull*)(ws + OFF_SS);
  int*       Athr    = (int*)(ws + OFF_ATHR);
  int*       Bthr    = (int*)(ws + OFF_BTHR);
  float*     hbuf    = (float*)(ws + OFF_H);
  uint32_t*  xbits   = (uint32_t*)(ws + OFF_XBITS);
  uint32_t*  w27     = xbits + 24576;
  float*     out     = (float*)d_out;

  zero_stats_k<<<6, 256, 0, stream>>>(Sg, SSg);

  pack_w_k<<<(9 * 4 * 256 + 255) / 256, 256, 0, stream>>>(w[1], wbits + 0,     256, 128);
  pack_w_k<<<(9 * 8 * 256 + 255) / 256, 256, 0, stream>>>(w[2], wbits + 9216,  256, 256);
  pack_w_k<<<(9 * 8 * 256 + 255) / 256, 256, 0, stream>>>(w[3], wbits + 27648, 256, 256);
  pack_w_k<<<(9 * 8 * 128 + 255) / 256, 256, 0, stream>>>(w[4], wbits + 46080, 128, 256);
  pack_w_k<<<(9 * 4 * 128 + 255) / 256, 256, 0, stream>>>(w[5], wbits + 55296, 128, 128);
  pack_x_k<<<96, 256, 0, stream>>>(x, xbits);
  pack_w0_k<<<1, 128, 0, stream>>>(w[0], w27);

  // L0: ci=3 co=128 H=32, no pool
  conv0x_k<<<256 * 4, 256, 0, stream>>>(xbits, w27, convout, Sg, SSg);
  finalize_k<<<1, 256, 0, stream>>>(Sg, SSg, Athr, Bthr, g[0], bt[0], 128, 262144);
  binarize_k<<<(256 * 4 * 34 * 34 + 255) / 256, 256, 0, stream>>>(
      convout, 128, 32, 32, 0, bitsA, Athr, Bthr, nullptr);

  // L1: ci=128 co=256 H=32, pool
  conv_xnor_k<4><<<256 * 16 * 4, 256, 0, stream>>>(bitsA, wbits + 0, convout,
                                                   Sg + 256, SSg + 256, 256, 32, 1152);
  finalize_k<<<1, 256, 0, stream>>>(Sg + 256, SSg + 256, Athr + 256, Bthr + 256, g[1], bt[1], 256, 262144);
  binarize_k<<<(256 * 8 * 18 * 18 + 255) / 256, 256, 0, stream>>>(
      convout, 256, 32, 32, 1, bitsB, Athr + 256, Bthr + 256, nullptr);

  // L2: ci=256 co=256 H=16, no pool
  conv_xnor_k<8><<<256 * 4 * 4, 256, 0, stream>>>(bitsB, wbits + 9216, convout,
                                                  Sg + 512, SSg + 512, 256, 16, 2304);
  finalize_k<<<1, 256, 0, stream>>>(Sg + 512, SSg + 512, Athr + 512, Bthr + 512, g[2], bt[2], 256, 65536);
  binarize_k<<<(256 * 8 * 18 * 18 + 255) / 256, 256, 0, stream>>>(
      convout, 256, 16, 16, 0, bitsA, Athr + 512, Bthr + 512, nullptr);

  // L3: ci=256 co=256 H=16, pool
  conv_xnor_k<8><<<256 * 4 * 4, 256, 0, stream>>>(bitsA, wbits + 27648, convout,
                                                  Sg + 768, SSg + 768, 256, 16, 2304);
  finalize_k<<<1, 256, 0, stream>>>(Sg + 768, SSg + 768, Athr + 768, Bthr + 768, g[3], bt[3], 256, 65536);
  binarize_k<<<(256 * 8 * 10 * 10 + 255) / 256, 256, 0, stream>>>(
      convout, 256, 16, 16, 1, bitsB, Athr + 768, Bthr + 768, nullptr);

  // L4: ci=256 co=128 H=8, no pool
  conv_xnor_k<8><<<256 * 2, 256, 0, stream>>>(bitsB, wbits + 46080, convout,
                                              Sg + 1024, SSg + 1024, 128, 8, 2304);
  finalize_k<<<1, 256, 0, stream>>>(Sg + 1024, SSg + 1024, Athr + 1024, Bthr + 1024, g[4], bt[4], 128, 16384);
  binarize_k<<<(256 * 4 * 10 * 10 + 255) / 256, 256, 0, stream>>>(
      convout, 128, 8, 8, 0, bitsA, Athr + 1024, Bthr + 1024, nullptr);

  // L5: ci=128 co=128 H=8, pool -> 4x4, also emit float h for FC
  conv_xnor_k<4><<<256 * 2, 256, 0, stream>>>(bitsA, wbits + 55296, convout,
                                              Sg + 1280, SSg + 1280, 128, 8, 1152);
  finalize_k<<<1, 256, 0, stream>>>(Sg + 1280, SSg + 1280, Athr + 1280, Bthr + 1280, g[5], bt[5], 128, 16384);
  binarize_k<<<(256 * 4 * 6 * 6 + 255) / 256, 256, 0, stream>>>(
      convout, 128, 8, 8, 1, bitsB, Athr + 1280, Bthr + 1280, hbuf);

  fc_k<<<256, 256, 0, stream>>>(hbuf, fcw, fcb, out);
}